// Round 12
// baseline (402.963 us; speedup 1.0000x reference)
//
#include <hip/hip_runtime.h>
#include <math.h>
#include <stdint.h>

#define N_U 60000
#define N_M 20000
#define NN  80000
#define EE  500000
#define BN_EPS 1e-5f
#define NB_SCAN 313   // ceil(80000/256)

typedef __attribute__((ext_vector_type(8))) short short8v;   // 8 bf16 = 4 VGPR (MFMA A/B frag)
typedef __attribute__((ext_vector_type(4))) float f32x4;     // MFMA C/D frag

// ---------------- bf16 helpers ----------------
__device__ __forceinline__ unsigned short bf_hi(float f) {
    unsigned u = __float_as_uint(f);
    return (unsigned short)((u + 0x7FFFu + ((u >> 16) & 1u)) >> 16);   // RNE
}
__device__ __forceinline__ float bf_f(unsigned short h) {
    return __uint_as_float(((unsigned)h) << 16);
}

// ---------------- prep: zero cnt/cursor/BN stats, rowptr[NN]=EE, detect edge dtype ----
__global__ void prep_kernel(const int* __restrict__ ei32, int* __restrict__ cnt,
                            int* __restrict__ cursor, int* __restrict__ rowptr,
                            float* __restrict__ sums, float* __restrict__ sumsq,
                            int* __restrict__ flag) {
    int i = blockIdx.x * blockDim.x + threadIdx.x;
    if (i < 256) { sums[i] = 0.f; sumsq[i] = 0.f; }
    for (int j = i; j < NN; j += gridDim.x * blockDim.x) { cnt[j] = 0; cursor[j] = 0; }
    if (i == 0) rowptr[NN] = EE;
    if (blockIdx.x == 0) {
        __shared__ int nz;
        if (threadIdx.x == 0) nz = 0;
        __syncthreads();
        int v = ei32[2 * threadIdx.x + 1];
        if (v != 0) atomicOr(&nz, 1);
        __syncthreads();
        if (threadIdx.x == 0) *flag = (nz == 0) ? 1 : 0;  // 1 -> int64
    }
}

__device__ __forceinline__ int load_idx(const void* ei, int f, int pos) {
    return f ? (int)((const long long*)ei)[pos] : ((const int*)ei)[pos];
}

// ---------------- degree histogram (dst side, edges only) ----------------
__global__ void hist_kernel(const void* __restrict__ ei, const int* __restrict__ flag,
                            int* __restrict__ cnt) {
    int f = *flag;
    int stride = gridDim.x * blockDim.x;
    for (int e = blockIdx.x * blockDim.x + threadIdx.x; e < EE; e += stride) {
        int d = load_idx(ei, f, EE + e);
        atomicAdd(&cnt[d], 1);
    }
}

// ---------------- exclusive scan of cnt -> rowptr (3 kernels); dinv fused in scan1 ----
__global__ void scan1_kernel(const int* __restrict__ cnt, int* __restrict__ rowptr,
                             int* __restrict__ blockSums, float* __restrict__ dinv) {
    __shared__ int sh[256];
    int tid = threadIdx.x;
    int i = blockIdx.x * 256 + tid;
    int v = (i < NN) ? cnt[i] : 0;
    int x = v;
    sh[tid] = x; __syncthreads();
#pragma unroll
    for (int off = 1; off < 256; off <<= 1) {
        int t = (tid >= off) ? sh[tid - off] : 0;
        __syncthreads();
        x += t; sh[tid] = x;
        __syncthreads();
    }
    if (i < NN) {
        rowptr[i] = x - v;
        dinv[i] = rsqrtf(1.0f + (float)v);   // +1 self-loop
    }
    if (tid == 255) blockSums[blockIdx.x] = x;
}

__global__ void scan2_kernel(int* __restrict__ blockSums) {
    __shared__ int sh[512];
    int tid = threadIdx.x;
    int v = (tid < NB_SCAN) ? blockSums[tid] : 0;
    int x = v;
    sh[tid] = x; __syncthreads();
#pragma unroll
    for (int off = 1; off < 512; off <<= 1) {
        int t = (tid >= off) ? sh[tid - off] : 0;
        __syncthreads();
        x += t; sh[tid] = x;
        __syncthreads();
    }
    if (tid < NB_SCAN) blockSums[tid] = x - v;
}

__global__ void scan3_kernel(int* __restrict__ rowptr, const int* __restrict__ blockSums) {
    int i = blockIdx.x * 256 + threadIdx.x;
    if (i < NN) rowptr[i] += blockSums[blockIdx.x];
}

// ---------------- CSR fill: csr_src grouped by dst ----------------
__global__ void fill_kernel(const void* __restrict__ ei, const int* __restrict__ flag,
                            const int* __restrict__ rowptr, int* __restrict__ cursor,
                            int* __restrict__ csr_src) {
    int f = *flag;
    int stride = gridDim.x * blockDim.x;
    for (int e = blockIdx.x * blockDim.x + threadIdx.x; e < EE; e += stride) {
        int s = load_idx(ei, f, e);
        int d = load_idx(ei, f, EE + e);
        int pos = rowptr[d] + atomicAdd(&cursor[d], 1);
        csr_src[pos] = s;
    }
}

// ---------------- all-W split into MFMA-fragment order (ONE launch) ----------------
// Fragment layout (matches GEMM B-load): nt=n>>4, r=n&15, kt=k>>5, q=(k>>3)&3, p=k&7
//   idx = ((nt*(K/32)+kt)<<9) + (q<<7) + (r<<3) + p   -> wave frag = contiguous 1 KiB
__device__ __forceinline__ void wfrag_store(const float* W, short* Hi, short* Lo,
                                            int i, int K, int N) {
    int k = i / N, n = i - k * N;
    float v = W[i];
    unsigned short h = bf_hi(v);
    unsigned short l = bf_hi(v - bf_f(h));
    int nt = n >> 4, r = n & 15, kt = k >> 5, q = (k >> 3) & 3, p = k & 7;
    int idx = ((nt * (K / 32) + kt) << 9) + (q << 7) + (r << 3) + p;
    Hi[idx] = (short)h;
    Lo[idx] = (short)l;
}

__global__ void wsplit_all_kernel(const float* __restrict__ W1, const float* __restrict__ W2,
                                  const float* __restrict__ Wf1, const float* __restrict__ Wf2,
                                  short* __restrict__ W1h, short* __restrict__ W1l,
                                  short* __restrict__ W2h, short* __restrict__ W2l,
                                  short* __restrict__ F1h, short* __restrict__ F1l,
                                  short* __restrict__ F2h, short* __restrict__ F2l) {
    int i = blockIdx.x * 256 + threadIdx.x;          // grid covers 65536
    if (i < 256 * 256) wfrag_store(W1, W1h, W1l, i, 256, 256);
    if (i < 256 * 128) wfrag_store(W2, W2h, W2l, i, 256, 128);
    if (i < 64 * 256)  wfrag_store(Wf1, F1h, F1l, i, 64, 256);
    if (i < 128 * 256) wfrag_store(Wf2, F2h, F2l, i, 128, 256);
}

// ---------------- split-bf16 MFMA GEMM (A via LDS, W via fragment-ordered L2) -------
// Block: 256 thr (4 waves, 2x2 of 64x64), tile 128x128, BK=32. LDS = A hi/lo only.
// AIN  0: A f32, split in-kernel (opt BNRELU: max(a*bnsc[k]+bnsh[k],0) first, exact f32)
// AIN  1: A pre-split bf16 hi/lo planes (no split VALU)
// MODE 0: v = (A@W)*ep[row];  MODE 1: v = (A@W)+ep[col]  (ragged M guarded)
// OUTK 0: f32 Out; 1: bf16 OutB; 2: bf16 hi/lo planes OutB/OutL
template <int K, int N, int MODE, int AIN, bool BNRELU, int OUTK>
__global__ __launch_bounds__(256) void mfma_gemm_kernel(
    int M, const float* __restrict__ A,
    const short* __restrict__ AHi, const short* __restrict__ ALo,
    const short* __restrict__ WfHi, const short* __restrict__ WfLo,
    const float* __restrict__ ep, const float* __restrict__ bnsc,
    const float* __restrict__ bnsh,
    float* __restrict__ Out, short* __restrict__ OutB, short* __restrict__ OutL) {
    constexpr int LDT = 40;   // padded LDS row stride (bf16): 80 B -> uniform 16B slots
    constexpr int NT = K / 32;
    __shared__ short AsHi[128 * LDT];
    __shared__ short AsLo[128 * LDT];
    const int tid  = threadIdx.x;
    const int lane = tid & 63, wave = tid >> 6;
    const int wm = (wave >> 1) * 64, wn = (wave & 1) * 64;
    const int R0 = blockIdx.x * 128;
    const int n0 = blockIdx.y * 128;
    const int srow  = tid >> 1;          // staging row 0..127 (2 thr/row)
    const int shalf = (tid & 1) * 16;    // element offset 0 / 16
    const int l15  = lane & 15;
    const int koff = (lane >> 4) * 8;    // k-slice base per lane
    const int nt0  = (n0 + wn) >> 4;     // base n-tile of this wave

    f32x4 acc[4][4];
#pragma unroll
    for (int mi = 0; mi < 4; ++mi)
#pragma unroll
        for (int ni = 0; ni < 4; ++ni)
            acc[mi][ni] = (f32x4){0.f, 0.f, 0.f, 0.f};

    const int arow = min(R0 + srow, M - 1);   // clamp for ragged tail (loads only)
    const float* abase = (AIN == 0) ? &A[(size_t)arow * K + shalf] : nullptr;
    const short* ahb   = (AIN == 1) ? &AHi[(size_t)arow * K + shalf] : nullptr;
    const short* alb   = (AIN == 1) ? &ALo[(size_t)arow * K + shalf] : nullptr;

    // ---- prologue: load A tile 0 ----
    float4 a0, a1, a2, a3;
    int4 th0, th1, tl0, tl1;
    if constexpr (AIN == 0) {
        const float4* ga = (const float4*)abase;
        a0 = ga[0]; a1 = ga[1]; a2 = ga[2]; a3 = ga[3];
    } else {
        th0 = ((const int4*)ahb)[0]; th1 = ((const int4*)ahb)[1];
        tl0 = ((const int4*)alb)[0]; tl1 = ((const int4*)alb)[1];
    }

#pragma unroll
    for (int kt = 0; kt < NT; ++kt) {
        const int k0 = kt * 32;
        int4 sh0, sh1, sl0, sl1;

        if constexpr (AIN == 0) {
            if (BNRELU) {   // fused BN-apply + ReLU on A (per-channel k), exact f32
                const float4* gs = (const float4*)&bnsc[k0 + shalf];
                const float4* gh = (const float4*)&bnsh[k0 + shalf];
                float4 s0 = gs[0], s1 = gs[1], s2 = gs[2], s3 = gs[3];
                float4 t0 = gh[0], t1 = gh[1], t2 = gh[2], t3 = gh[3];
#define BNR4(a, s, t)                                                          \
                a.x = fmaxf(a.x * s.x + t.x, 0.f);                             \
                a.y = fmaxf(a.y * s.y + t.y, 0.f);                             \
                a.z = fmaxf(a.z * s.z + t.z, 0.f);                             \
                a.w = fmaxf(a.w * s.w + t.w, 0.f);
                BNR4(a0, s0, t0); BNR4(a1, s1, t1); BNR4(a2, s2, t2); BNR4(a3, s3, t3);
#undef BNR4
            }
            unsigned h[8], l[8];
#define SPLIT4(v, hA, hB, lA, lB)                                              \
            {                                                                  \
                unsigned short h0_ = bf_hi(v.x), h1_ = bf_hi(v.y);             \
                unsigned short h2_ = bf_hi(v.z), h3_ = bf_hi(v.w);             \
                unsigned short l0_ = bf_hi(v.x - bf_f(h0_));                   \
                unsigned short l1_ = bf_hi(v.y - bf_f(h1_));                   \
                unsigned short l2_ = bf_hi(v.z - bf_f(h2_));                   \
                unsigned short l3_ = bf_hi(v.w - bf_f(h3_));                   \
                hA = (unsigned)h0_ | ((unsigned)h1_ << 16);                    \
                hB = (unsigned)h2_ | ((unsigned)h3_ << 16);                    \
                lA = (unsigned)l0_ | ((unsigned)l1_ << 16);                    \
                lB = (unsigned)l2_ | ((unsigned)l3_ << 16);                    \
            }
            SPLIT4(a0, h[0], h[1], l[0], l[1]);
            SPLIT4(a1, h[2], h[3], l[2], l[3]);
            SPLIT4(a2, h[4], h[5], l[4], l[5]);
            SPLIT4(a3, h[6], h[7], l[6], l[7]);
#undef SPLIT4
            sh0 = make_int4((int)h[0], (int)h[1], (int)h[2], (int)h[3]);
            sh1 = make_int4((int)h[4], (int)h[5], (int)h[6], (int)h[7]);
            sl0 = make_int4((int)l[0], (int)l[1], (int)l[2], (int)l[3]);
            sl1 = make_int4((int)l[4], (int)l[5], (int)l[6], (int)l[7]);
        } else {
            sh0 = th0; sh1 = th1; sl0 = tl0; sl1 = tl1;
        }

        __syncthreads();   // previous iteration done reading LDS
        int4* dAH = (int4*)&AsHi[srow * LDT + shalf];
        int4* dAL = (int4*)&AsLo[srow * LDT + shalf];
        dAH[0] = sh0; dAH[1] = sh1;
        dAL[0] = sl0; dAL[1] = sl1;
        __syncthreads();

        // ---- prefetch next A tile (latency hides under MFMA below) ----
        if (kt + 1 < NT) {
            if constexpr (AIN == 0) {
                const float4* gnext = (const float4*)(abase + (kt + 1) * 32);
                a0 = gnext[0]; a1 = gnext[1]; a2 = gnext[2]; a3 = gnext[3];
            } else {
                const int4* gh = (const int4*)(ahb + (kt + 1) * 32);
                const int4* gl = (const int4*)(alb + (kt + 1) * 32);
                th0 = gh[0]; th1 = gh[1]; tl0 = gl[0]; tl1 = gl[1];
            }
        }

        // ---- W fragments straight from global (L2-resident, fully coalesced) ----
        short8v bh[4], bl[4];
#pragma unroll
        for (int ni = 0; ni < 4; ++ni) {
            int fidx = (((nt0 + ni) * NT + kt) << 9) + lane * 8;
            bh[ni] = *(const short8v*)&WfHi[fidx];
            bl[ni] = *(const short8v*)&WfLo[fidx];
        }

        // ---- A frags + MFMA (AhWh + AhWl + AlWh; fp32 accum) ----
#pragma unroll
        for (int mi = 0; mi < 4; ++mi) {
            int mrow = wm + mi * 16 + l15;
            short8v ah = *(const short8v*)&AsHi[mrow * LDT + koff];
            short8v al = *(const short8v*)&AsLo[mrow * LDT + koff];
#pragma unroll
            for (int ni = 0; ni < 4; ++ni) {
                acc[mi][ni] = __builtin_amdgcn_mfma_f32_16x16x32_bf16(ah, bh[ni], acc[mi][ni], 0, 0, 0);
                acc[mi][ni] = __builtin_amdgcn_mfma_f32_16x16x32_bf16(ah, bl[ni], acc[mi][ni], 0, 0, 0);
                acc[mi][ni] = __builtin_amdgcn_mfma_f32_16x16x32_bf16(al, bh[ni], acc[mi][ni], 0, 0, 0);
            }
        }
    }

    // ---- epilogue: C/D layout col=lane&15, row=(lane>>4)*4+i ----
#pragma unroll
    for (int mi = 0; mi < 4; ++mi) {
#pragma unroll
        for (int i = 0; i < 4; ++i) {
            int row = R0 + wm + mi * 16 + (lane >> 4) * 4 + i;
            if (row < M) {
                float sc = (MODE == 0) ? ep[row] : 1.0f;
#pragma unroll
                for (int ni = 0; ni < 4; ++ni) {
                    int col = n0 + wn + ni * 16 + l15;
                    float v = acc[mi][ni][i];
                    v = (MODE == 0) ? v * sc : v + ep[col];
                    if constexpr (OUTK == 0) {
                        Out[(size_t)row * N + col] = v;
                    } else if constexpr (OUTK == 1) {
                        OutB[(size_t)row * N + col] = (short)bf_hi(v);
                    } else {
                        unsigned short h = bf_hi(v);
                        OutB[(size_t)row * N + col] = (short)h;
                        OutL[(size_t)row * N + col] = (short)bf_hi(v - bf_f(h));
                    }
                }
            }
        }
    }
}

// ---------------- gather aggregation (no atomics; bf16 h, f32 accumulate/out) -------
// h pre-scaled by dinv[row]:  out[d] = bias + dinv[d]*( h'[d] + sum_{s in N(d)} h'[s] )
__device__ __forceinline__ void acc_bf4(float4& a, ushort4 v) {
    a.x += bf_f(v.x); a.y += bf_f(v.y); a.z += bf_f(v.z); a.w += bf_f(v.w);
}

__global__ __launch_bounds__(256) void gather256_kernel(const short* __restrict__ h,
                                                        const float* __restrict__ bias,
                                                        const float* __restrict__ dinv,
                                                        const int* __restrict__ rowptr,
                                                        const int* __restrict__ csr_src,
                                                        float* __restrict__ out) {
    int wid = threadIdx.x >> 6, lane = threadIdx.x & 63;   // wave per row; 4 ch/lane
    int r = blockIdx.x * 4 + wid;
    if (r >= NN) return;
    int beg = rowptr[r], end = rowptr[r + 1];
    float dr = dinv[r];
    const ushort4* hp = (const ushort4*)h;                 // row stride 64 ushort4
    float4 acc = {0.f, 0.f, 0.f, 0.f};
    acc_bf4(acc, hp[(size_t)r * 64 + lane]);               // self (pre-scaled)
    int k = beg;
    for (; k + 3 < end; k += 4) {                          // 4 row loads in flight
        int s0 = csr_src[k], s1 = csr_src[k + 1], s2 = csr_src[k + 2], s3 = csr_src[k + 3];
        ushort4 v0 = hp[(size_t)s0 * 64 + lane];
        ushort4 v1 = hp[(size_t)s1 * 64 + lane];
        ushort4 v2 = hp[(size_t)s2 * 64 + lane];
        ushort4 v3 = hp[(size_t)s3 * 64 + lane];
        acc_bf4(acc, v0); acc_bf4(acc, v1); acc_bf4(acc, v2); acc_bf4(acc, v3);
    }
    for (; k < end; ++k)
        acc_bf4(acc, hp[(size_t)csr_src[k] * 64 + lane]);
    float4 b = ((const float4*)bias)[lane];
    float4 o;
    o.x = b.x + dr * acc.x; o.y = b.y + dr * acc.y;
    o.z = b.z + dr * acc.z; o.w = b.w + dr * acc.w;
    ((float4*)(out + (size_t)r * 256))[lane] = o;
}

__global__ __launch_bounds__(256) void gather128_kernel(const short* __restrict__ h,
                                                        const float* __restrict__ bias,
                                                        const float* __restrict__ dinv,
                                                        const int* __restrict__ rowptr,
                                                        const int* __restrict__ csr_src,
                                                        float* __restrict__ out) {
    int sub = threadIdx.x >> 5, lane = threadIdx.x & 31;   // half-wave per row; 4 ch/lane
    int r = blockIdx.x * 8 + sub;
    if (r >= NN) return;
    int beg = rowptr[r], end = rowptr[r + 1];
    float dr = dinv[r];
    const ushort4* hp = (const ushort4*)h;                 // row stride 32 ushort4
    float4 acc = {0.f, 0.f, 0.f, 0.f};
    acc_bf4(acc, hp[(size_t)r * 32 + lane]);
    int k = beg;
    for (; k + 3 < end; k += 4) {
        int s0 = csr_src[k], s1 = csr_src[k + 1], s2 = csr_src[k + 2], s3 = csr_src[k + 3];
        ushort4 v0 = hp[(size_t)s0 * 32 + lane];
        ushort4 v1 = hp[(size_t)s1 * 32 + lane];
        ushort4 v2 = hp[(size_t)s2 * 32 + lane];
        ushort4 v3 = hp[(size_t)s3 * 32 + lane];
        acc_bf4(acc, v0); acc_bf4(acc, v1); acc_bf4(acc, v2); acc_bf4(acc, v3);
    }
    for (; k < end; ++k)
        acc_bf4(acc, hp[(size_t)csr_src[k] * 32 + lane]);
    float4 b = ((const float4*)bias)[lane];
    float4 o;
    o.x = b.x + dr * acc.x; o.y = b.y + dr * acc.y;
    o.z = b.z + dr * acc.z; o.w = b.w + dr * acc.w;
    ((float4*)(out + (size_t)r * 128))[lane] = o;
}

// ---------------- BN stats (vectorized, LDS-reduced) / finalize ----------------
__global__ __launch_bounds__(256) void bn_stats_kernel(const float* __restrict__ a,
                                                       float* __restrict__ sums,
                                                       float* __restrict__ sumsq) {
    __shared__ float shs[256], shs2[256];
    int tid = threadIdx.x;
    int wid = tid >> 6, lane = tid & 63;                   // 4 waves; float4/lane
    shs[tid] = 0.f; shs2[tid] = 0.f;
    __syncthreads();
    float4 s = {0.f, 0.f, 0.f, 0.f}, s2 = {0.f, 0.f, 0.f, 0.f};
    for (int row = blockIdx.x * 4 + wid; row < NN; row += gridDim.x * 4) {
        float4 v = ((const float4*)(a + (size_t)row * 256))[lane];
        s.x += v.x; s.y += v.y; s.z += v.z; s.w += v.w;
        s2.x += v.x * v.x; s2.y += v.y * v.y; s2.z += v.z * v.z; s2.w += v.w * v.w;
    }
    atomicAdd(&shs[4 * lane + 0], s.x);  atomicAdd(&shs2[4 * lane + 0], s2.x);
    atomicAdd(&shs[4 * lane + 1], s.y);  atomicAdd(&shs2[4 * lane + 1], s2.y);
    atomicAdd(&shs[4 * lane + 2], s.z);  atomicAdd(&shs2[4 * lane + 2], s2.z);
    atomicAdd(&shs[4 * lane + 3], s.w);  atomicAdd(&shs2[4 * lane + 3], s2.w);
    __syncthreads();
    atomicAdd(&sums[tid], shs[tid]);
    atomicAdd(&sumsq[tid], shs2[tid]);
}

__global__ void bn_final_kernel(const float* __restrict__ sums, const float* __restrict__ sumsq,
                                const float* __restrict__ gamma, const float* __restrict__ beta,
                                float* __restrict__ scale, float* __restrict__ shift) {
    int c = threadIdx.x;
    const float Nf = (float)NN;
    float mean = sums[c] / Nf;
    float var = sumsq[c] / Nf - mean * mean;
    float sc = gamma[c] * rsqrtf(var + BN_EPS);
    scale[c] = sc;
    shift[c] = beta[c] - mean * sc;
}

extern "C" void kernel_launch(void* const* d_in, const int* in_sizes, int n_in,
                              void* d_out, int out_size, void* d_ws, size_t ws_size,
                              hipStream_t stream) {
    const float* x       = (const float*)d_in[0];
    const float* y       = (const float*)d_in[1];
    const void*  ei      = d_in[2];
    const float* fc1_w   = (const float*)d_in[3];
    const float* fc1_b   = (const float*)d_in[4];
    const float* fc2_w   = (const float*)d_in[5];
    const float* fc2_b   = (const float*)d_in[6];
    const float* conv1_w = (const float*)d_in[7];
    const float* conv1_b = (const float*)d_in[8];
    const float* conv2_w = (const float*)d_in[9];
    const float* conv2_b = (const float*)d_in[10];
    const float* gamma   = (const float*)d_in[11];
    const float* beta    = (const float*)d_in[12];
    float* out = (float*)d_out;

    // Buffer ping-pong (zero extra workspace vs round 8):
    //  bufB region: z0 hi/lo planes (fc out, conv1 in) -> a1 f32 (gather256 out, conv2 in)
    //  bufA region: h1' bf16 (conv1 out, gather256 in) -> h2' bf16 (conv2 out, gather128 in)
    float* ws = (float*)d_ws;
    float* bufA = ws;                       // NN*256 f32 worth
    float* bufB = ws + (size_t)NN * 256;    // NN*256 f32 worth
    float* aux  = bufB + (size_t)NN * 256;
    float* dinv  = aux;                      // NN
    float* sums  = dinv + NN;                // 256
    float* sumsq = sums + 256;               // 256
    float* scale = sumsq + 256;              // 256
    float* shift = scale + 256;              // 256
    int*   flag      = (int*)(shift + 256);  // 1
    int*   cnt       = flag + 1;             // NN
    int*   rowptr    = cnt + NN;             // NN+1
    int*   cursor    = rowptr + NN + 1;      // NN
    int*   blockSums = cursor + NN;          // NB_SCAN
    int*   csr_src   = blockSums + NB_SCAN + 3;  // EE
    // 16B-aligned fragment-ordered W buffers after csr
    short* w1th = (short*)(((uintptr_t)(csr_src + EE) + 15) & ~(uintptr_t)15);
    short* w1tl = w1th + 256 * 256;
    short* w2th = w1tl + 256 * 256;
    short* w2tl = w2th + 256 * 128;
    short* wf1h = w2tl + 256 * 128;
    short* wf1l = wf1h + 256 * 64;
    short* wf2h = wf1l + 256 * 64;
    short* wf2l = wf2h + 256 * 128;

    short* zHi = (short*)bufB;               // NN*256 bf16
    short* zLo = zHi + (size_t)NN * 256;     // NN*256 bf16 (fills rest of bufB region)
    short* hA  = (short*)bufA;               // h1'/h2' bf16 plane in bufA region
    float* a1  = bufB;                       // a1 f32 (reuses bufB after z planes die)

    // ---- CSR build + W fragment split (one launch) ----
    prep_kernel<<<320, 256, 0, stream>>>((const int*)ei, cnt, cursor, rowptr, sums, sumsq, flag);
    hist_kernel<<<1024, 256, 0, stream>>>(ei, flag, cnt);
    scan1_kernel<<<NB_SCAN, 256, 0, stream>>>(cnt, rowptr, blockSums, dinv);
    scan2_kernel<<<1, 512, 0, stream>>>(blockSums);
    scan3_kernel<<<NB_SCAN, 256, 0, stream>>>(rowptr, blockSums);
    fill_kernel<<<1024, 256, 0, stream>>>(ei, flag, rowptr, cursor, csr_src);
    wsplit_all_kernel<<<256, 256, 0, stream>>>(conv1_w, conv2_w, fc1_w, fc2_w,
                                               w1th, w1tl, w2th, w2tl,
                                               wf1h, wf1l, wf2h, wf2l);

    // ---- input projections -> z0 hi/lo planes (ragged M guarded) ----
    mfma_gemm_kernel<64, 256, 1, 0, false, 2><<<dim3(469, 2), 256, 0, stream>>>(
        N_U, x, nullptr, nullptr, wf1h, wf1l, fc1_b, nullptr, nullptr,
        nullptr, zHi, zLo);
    mfma_gemm_kernel<128, 256, 1, 0, false, 2><<<dim3(157, 2), 256, 0, stream>>>(
        N_M, y, nullptr, nullptr, wf2h, wf2l, fc2_b, nullptr, nullptr,
        nullptr, zHi + (size_t)N_U * 256, zLo + (size_t)N_U * 256);

    // ---- conv1: h1' = (z0 @ W1) * dinv -> bf16 hA; gather -> a1 f32 ----
    mfma_gemm_kernel<256, 256, 0, 1, false, 1><<<dim3(625, 2), 256, 0, stream>>>(
        NN, nullptr, zHi, zLo, w1th, w1tl, dinv, nullptr, nullptr,
        nullptr, hA, nullptr);
    gather256_kernel<<<NN / 4, 256, 0, stream>>>(hA, conv1_b, dinv, rowptr, csr_src, a1);

    // ---- BN stats on raw a1; apply+ReLU fused into conv2's A-path ----
    bn_stats_kernel<<<256, 256, 0, stream>>>(a1, sums, sumsq);
    bn_final_kernel<<<1, 256, 0, stream>>>(sums, sumsq, gamma, beta, scale, shift);

    // ---- conv2: h2' = (relu(bn(a1)) @ W2) * dinv -> bf16 hA; gather -> out ----
    mfma_gemm_kernel<256, 128, 0, 0, true, 1><<<dim3(625, 1), 256, 0, stream>>>(
        NN, a1, nullptr, nullptr, w2th, w2tl, dinv, scale, shift,
        nullptr, hA, nullptr);
    gather128_kernel<<<NN / 8, 256, 0, stream>>>(hA, conv2_b, dinv, rowptr, csr_src, out);
}

// Round 13
// 390.158 us; speedup vs baseline: 1.0328x; 1.0328x over previous
//
#include <hip/hip_runtime.h>
#include <math.h>
#include <stdint.h>

#define N_U 60000
#define N_M 20000
#define NN  80000
#define EE  500000
#define BN_EPS 1e-5f
#define NB_SCAN 313   // ceil(80000/256)
#define GBLK 1024     // gather256 grid (grid-stride; all blocks co-resident)

typedef __attribute__((ext_vector_type(8))) short short8v;   // 8 bf16 = 4 VGPR (MFMA A/B frag)
typedef __attribute__((ext_vector_type(4))) float f32x4;     // MFMA C/D frag

// ---------------- bf16 helpers ----------------
__device__ __forceinline__ unsigned short bf_hi(float f) {
    unsigned u = __float_as_uint(f);
    return (unsigned short)((u + 0x7FFFu + ((u >> 16) & 1u)) >> 16);   // RNE
}
__device__ __forceinline__ float bf_f(unsigned short h) {
    return __uint_as_float(((unsigned)h) << 16);
}

// ---------------- W fragment store (MFMA B-operand order) ----------------
// nt=n>>4, r=n&15, kt=k>>5, q=(k>>3)&3, p=k&7
//   idx = ((nt*(K/32)+kt)<<9) + (q<<7) + (r<<3) + p   -> wave frag = contiguous 1 KiB
__device__ __forceinline__ void wfrag_store(const float* W, short* Hi, short* Lo,
                                            int i, int K, int N) {
    int k = i / N, n = i - k * N;
    float v = W[i];
    unsigned short h = bf_hi(v);
    unsigned short l = bf_hi(v - bf_f(h));
    int nt = n >> 4, r = n & 15, kt = k >> 5, q = (k >> 3) & 3, p = k & 7;
    int idx = ((nt * (K / 32) + kt) << 9) + (q << 7) + (r << 3) + p;
    Hi[idx] = (short)h;
    Lo[idx] = (short)l;
}

// ---------------- prep: zero state, detect edge dtype, split all W ----------------
__global__ void prep_kernel(const int* __restrict__ ei32, int* __restrict__ cnt,
                            int* __restrict__ cursor, int* __restrict__ rowptr,
                            float* __restrict__ sums, float* __restrict__ sumsq,
                            int* __restrict__ flag,
                            const float* __restrict__ W1, const float* __restrict__ W2,
                            const float* __restrict__ Wf1, const float* __restrict__ Wf2,
                            short* __restrict__ W1h, short* __restrict__ W1l,
                            short* __restrict__ W2h, short* __restrict__ W2l,
                            short* __restrict__ F1h, short* __restrict__ F1l,
                            short* __restrict__ F2h, short* __restrict__ F2l) {
    int i = blockIdx.x * blockDim.x + threadIdx.x;
    if (i < 256) { sums[i] = 0.f; sumsq[i] = 0.f; }
    for (int j = i; j < NN; j += gridDim.x * blockDim.x) { cnt[j] = 0; cursor[j] = 0; }
    if (i == 0) rowptr[NN] = EE;
    // W fragment split (i covers 65536 with 320*256 = 81920 threads)
    if (i < 256 * 256) wfrag_store(W1, W1h, W1l, i, 256, 256);
    if (i < 256 * 128) wfrag_store(W2, W2h, W2l, i, 256, 128);
    if (i < 64 * 256)  wfrag_store(Wf1, F1h, F1l, i, 64, 256);
    if (i < 128 * 256) wfrag_store(Wf2, F2h, F2l, i, 128, 256);
    if (blockIdx.x == 0) {
        __shared__ int nz;
        if (threadIdx.x == 0) nz = 0;
        __syncthreads();
        int v = ei32[2 * threadIdx.x + 1];
        if (v != 0) atomicOr(&nz, 1);
        __syncthreads();
        if (threadIdx.x == 0) *flag = (nz == 0) ? 1 : 0;  // 1 -> int64
    }
}

__device__ __forceinline__ int load_idx(const void* ei, int f, int pos) {
    return f ? (int)((const long long*)ei)[pos] : ((const int*)ei)[pos];
}

// ---------------- degree histogram (dst side, edges only) ----------------
__global__ void hist_kernel(const void* __restrict__ ei, const int* __restrict__ flag,
                            int* __restrict__ cnt) {
    int f = *flag;
    int stride = gridDim.x * blockDim.x;
    for (int e = blockIdx.x * blockDim.x + threadIdx.x; e < EE; e += stride) {
        int d = load_idx(ei, f, EE + e);
        atomicAdd(&cnt[d], 1);
    }
}

// ---------------- scan1: in-block exclusive scan + block totals + dinv --------------
__global__ void scan1_kernel(const int* __restrict__ cnt, int* __restrict__ rowptr,
                             int* __restrict__ blockSums, float* __restrict__ dinv) {
    __shared__ int sh[256];
    int tid = threadIdx.x;
    int i = blockIdx.x * 256 + tid;
    int v = (i < NN) ? cnt[i] : 0;
    int x = v;
    sh[tid] = x; __syncthreads();
#pragma unroll
    for (int off = 1; off < 256; off <<= 1) {
        int t = (tid >= off) ? sh[tid - off] : 0;
        __syncthreads();
        x += t; sh[tid] = x;
        __syncthreads();
    }
    if (i < NN) {
        rowptr[i] = x - v;
        dinv[i] = rsqrtf(1.0f + (float)v);   // +1 self-loop
    }
    if (tid == 255) blockSums[blockIdx.x] = x;
}

// ---------------- scan3: per-block prefix via reduction of blockSums[0..b) ---------
__global__ void scan3_kernel(int* __restrict__ rowptr, const int* __restrict__ blockSums) {
    __shared__ int red[256];
    int b = blockIdx.x, tid = threadIdx.x;
    int s = 0;
    for (int j = tid; j < b; j += 256) s += blockSums[j];
    red[tid] = s; __syncthreads();
#pragma unroll
    for (int off = 128; off > 0; off >>= 1) {
        if (tid < off) red[tid] += red[tid + off];
        __syncthreads();
    }
    int base = red[0];
    int i = b * 256 + tid;
    if (i < NN) rowptr[i] += base;
}

// ---------------- CSR fill: csr_src grouped by dst ----------------
__global__ void fill_kernel(const void* __restrict__ ei, const int* __restrict__ flag,
                            const int* __restrict__ rowptr, int* __restrict__ cursor,
                            int* __restrict__ csr_src) {
    int f = *flag;
    int stride = gridDim.x * blockDim.x;
    for (int e = blockIdx.x * blockDim.x + threadIdx.x; e < EE; e += stride) {
        int s = load_idx(ei, f, e);
        int d = load_idx(ei, f, EE + e);
        int pos = rowptr[d] + atomicAdd(&cursor[d], 1);
        csr_src[pos] = s;
    }
}

// ---------------- split-bf16 MFMA GEMM body (A via LDS, W via fragment L2) ---------
// 256 thr (4 waves, 2x2 of 64x64), tile 128x128, BK=32. LDS = A hi/lo only.
// AIN 0: A f32 split in-kernel (opt BNRELU first, exact f32); AIN 1: pre-split planes
// MODE 0: v=(A@W)*ep[row]; MODE 1: v=(A@W)+ep[col] (ragged M guarded)
// OUTK 0: f32; 1: bf16; 2: bf16 hi/lo planes
template <int K, int N, int MODE, int AIN, bool BNRELU, int OUTK>
__device__ __forceinline__ void mfma_gemm_body(
    int M, int bx, int by, short* AsHi, short* AsLo,
    const float* __restrict__ A,
    const short* __restrict__ AHi, const short* __restrict__ ALo,
    const short* __restrict__ WfHi, const short* __restrict__ WfLo,
    const float* __restrict__ ep, const float* __restrict__ bnsc,
    const float* __restrict__ bnsh,
    float* __restrict__ Out, short* __restrict__ OutB, short* __restrict__ OutL) {
    constexpr int LDT = 40;   // padded LDS row stride (bf16): 80 B -> uniform 16B slots
    constexpr int NT = K / 32;
    const int tid  = threadIdx.x;
    const int lane = tid & 63, wave = tid >> 6;
    const int wm = (wave >> 1) * 64, wn = (wave & 1) * 64;
    const int R0 = bx * 128;
    const int n0 = by * 128;
    const int srow  = tid >> 1;          // staging row 0..127 (2 thr/row)
    const int shalf = (tid & 1) * 16;    // element offset 0 / 16
    const int l15  = lane & 15;
    const int koff = (lane >> 4) * 8;    // k-slice base per lane
    const int nt0  = (n0 + wn) >> 4;     // base n-tile of this wave

    f32x4 acc[4][4];
#pragma unroll
    for (int mi = 0; mi < 4; ++mi)
#pragma unroll
        for (int ni = 0; ni < 4; ++ni)
            acc[mi][ni] = (f32x4){0.f, 0.f, 0.f, 0.f};

    const int arow = min(R0 + srow, M - 1);   // clamp for ragged tail (loads only)
    const float* abase = (AIN == 0) ? &A[(size_t)arow * K + shalf] : nullptr;
    const short* ahb   = (AIN == 1) ? &AHi[(size_t)arow * K + shalf] : nullptr;
    const short* alb   = (AIN == 1) ? &ALo[(size_t)arow * K + shalf] : nullptr;

    // ---- prologue: load A tile 0 ----
    float4 a0, a1, a2, a3;
    int4 th0, th1, tl0, tl1;
    if constexpr (AIN == 0) {
        const float4* ga = (const float4*)abase;
        a0 = ga[0]; a1 = ga[1]; a2 = ga[2]; a3 = ga[3];
    } else {
        th0 = ((const int4*)ahb)[0]; th1 = ((const int4*)ahb)[1];
        tl0 = ((const int4*)alb)[0]; tl1 = ((const int4*)alb)[1];
    }

#pragma unroll
    for (int kt = 0; kt < NT; ++kt) {
        const int k0 = kt * 32;
        int4 sh0, sh1, sl0, sl1;

        if constexpr (AIN == 0) {
            if (BNRELU) {   // fused BN-apply + ReLU on A (per-channel k), exact f32
                const float4* gs = (const float4*)&bnsc[k0 + shalf];
                const float4* gh = (const float4*)&bnsh[k0 + shalf];
                float4 s0 = gs[0], s1 = gs[1], s2 = gs[2], s3 = gs[3];
                float4 t0 = gh[0], t1 = gh[1], t2 = gh[2], t3 = gh[3];
#define BNR4(a, s, t)                                                          \
                a.x = fmaxf(a.x * s.x + t.x, 0.f);                             \
                a.y = fmaxf(a.y * s.y + t.y, 0.f);                             \
                a.z = fmaxf(a.z * s.z + t.z, 0.f);                             \
                a.w = fmaxf(a.w * s.w + t.w, 0.f);
                BNR4(a0, s0, t0); BNR4(a1, s1, t1); BNR4(a2, s2, t2); BNR4(a3, s3, t3);
#undef BNR4
            }
            unsigned h[8], l[8];
#define SPLIT4(v, hA, hB, lA, lB)                                              \
            {                                                                  \
                unsigned short h0_ = bf_hi(v.x), h1_ = bf_hi(v.y);             \
                unsigned short h2_ = bf_hi(v.z), h3_ = bf_hi(v.w);             \
                unsigned short l0_ = bf_hi(v.x - bf_f(h0_));                   \
                unsigned short l1_ = bf_hi(v.y - bf_f(h1_));                   \
                unsigned short l2_ = bf_hi(v.z - bf_f(h2_));                   \
                unsigned short l3_ = bf_hi(v.w - bf_f(h3_));                   \
                hA = (unsigned)h0_ | ((unsigned)h1_ << 16);                    \
                hB = (unsigned)h2_ | ((unsigned)h3_ << 16);                    \
                lA = (unsigned)l0_ | ((unsigned)l1_ << 16);                    \
                lB = (unsigned)l2_ | ((unsigned)l3_ << 16);                    \
            }
            SPLIT4(a0, h[0], h[1], l[0], l[1]);
            SPLIT4(a1, h[2], h[3], l[2], l[3]);
            SPLIT4(a2, h[4], h[5], l[4], l[5]);
            SPLIT4(a3, h[6], h[7], l[6], l[7]);
#undef SPLIT4
            sh0 = make_int4((int)h[0], (int)h[1], (int)h[2], (int)h[3]);
            sh1 = make_int4((int)h[4], (int)h[5], (int)h[6], (int)h[7]);
            sl0 = make_int4((int)l[0], (int)l[1], (int)l[2], (int)l[3]);
            sl1 = make_int4((int)l[4], (int)l[5], (int)l[6], (int)l[7]);
        } else {
            sh0 = th0; sh1 = th1; sl0 = tl0; sl1 = tl1;
        }

        __syncthreads();   // previous iteration done reading LDS
        int4* dAH = (int4*)&AsHi[srow * LDT + shalf];
        int4* dAL = (int4*)&AsLo[srow * LDT + shalf];
        dAH[0] = sh0; dAH[1] = sh1;
        dAL[0] = sl0; dAL[1] = sl1;
        __syncthreads();

        // ---- prefetch next A tile (latency hides under MFMA below) ----
        if (kt + 1 < NT) {
            if constexpr (AIN == 0) {
                const float4* gnext = (const float4*)(abase + (kt + 1) * 32);
                a0 = gnext[0]; a1 = gnext[1]; a2 = gnext[2]; a3 = gnext[3];
            } else {
                const int4* gh = (const int4*)(ahb + (kt + 1) * 32);
                const int4* gl = (const int4*)(alb + (kt + 1) * 32);
                th0 = gh[0]; th1 = gh[1]; tl0 = gl[0]; tl1 = gl[1];
            }
        }

        // ---- W fragments straight from global (L2-resident, fully coalesced) ----
        short8v bh[4], bl[4];
#pragma unroll
        for (int ni = 0; ni < 4; ++ni) {
            int fidx = (((nt0 + ni) * NT + kt) << 9) + lane * 8;
            bh[ni] = *(const short8v*)&WfHi[fidx];
            bl[ni] = *(const short8v*)&WfLo[fidx];
        }

        // ---- A frags + MFMA (AhWh + AhWl + AlWh; fp32 accum) ----
#pragma unroll
        for (int mi = 0; mi < 4; ++mi) {
            int mrow = wm + mi * 16 + l15;
            short8v ah = *(const short8v*)&AsHi[mrow * LDT + koff];
            short8v al = *(const short8v*)&AsLo[mrow * LDT + koff];
#pragma unroll
            for (int ni = 0; ni < 4; ++ni) {
                acc[mi][ni] = __builtin_amdgcn_mfma_f32_16x16x32_bf16(ah, bh[ni], acc[mi][ni], 0, 0, 0);
                acc[mi][ni] = __builtin_amdgcn_mfma_f32_16x16x32_bf16(ah, bl[ni], acc[mi][ni], 0, 0, 0);
                acc[mi][ni] = __builtin_amdgcn_mfma_f32_16x16x32_bf16(al, bh[ni], acc[mi][ni], 0, 0, 0);
            }
        }
    }

    // ---- epilogue: C/D layout col=lane&15, row=(lane>>4)*4+i ----
#pragma unroll
    for (int mi = 0; mi < 4; ++mi) {
#pragma unroll
        for (int i = 0; i < 4; ++i) {
            int row = R0 + wm + mi * 16 + (lane >> 4) * 4 + i;
            if (row < M) {
                float sc = (MODE == 0) ? ep[row] : 1.0f;
#pragma unroll
                for (int ni = 0; ni < 4; ++ni) {
                    int col = n0 + wn + ni * 16 + l15;
                    float v = acc[mi][ni][i];
                    v = (MODE == 0) ? v * sc : v + ep[col];
                    if constexpr (OUTK == 0) {
                        Out[(size_t)row * N + col] = v;
                    } else if constexpr (OUTK == 1) {
                        OutB[(size_t)row * N + col] = (short)bf_hi(v);
                    } else {
                        unsigned short h = bf_hi(v);
                        OutB[(size_t)row * N + col] = (short)h;
                        OutL[(size_t)row * N + col] = (short)bf_hi(v - bf_f(h));
                    }
                }
            }
        }
    }
}

// conv wrappers (own static LDS)
template <int K, int N, int MODE, int AIN, bool BNRELU, int OUTK>
__global__ __launch_bounds__(256) void mfma_gemm_kernel(
    int M, const float* __restrict__ A,
    const short* __restrict__ AHi, const short* __restrict__ ALo,
    const short* __restrict__ WfHi, const short* __restrict__ WfLo,
    const float* __restrict__ ep, const float* __restrict__ bnsc,
    const float* __restrict__ bnsh,
    float* __restrict__ Out, short* __restrict__ OutB, short* __restrict__ OutL) {
    __shared__ short AsHi[128 * 40];
    __shared__ short AsLo[128 * 40];
    mfma_gemm_body<K, N, MODE, AIN, BNRELU, OUTK>(
        M, blockIdx.x, blockIdx.y, AsHi, AsLo, A, AHi, ALo, WfHi, WfLo,
        ep, bnsc, bnsh, Out, OutB, OutL);
}

// fc1+fc2 in one launch: blocks [0,938) -> fc1 (469x2), [938,1252) -> fc2 (157x2)
__global__ __launch_bounds__(256) void fc_combined_kernel(
    const float* __restrict__ x, const float* __restrict__ y,
    const short* __restrict__ wf1h, const short* __restrict__ wf1l,
    const short* __restrict__ wf2h, const short* __restrict__ wf2l,
    const float* __restrict__ fc1_b, const float* __restrict__ fc2_b,
    short* __restrict__ zHi, short* __restrict__ zLo) {
    __shared__ short AsHi[128 * 40];
    __shared__ short AsLo[128 * 40];
    int b = blockIdx.x;
    if (b < 938) {
        mfma_gemm_body<64, 256, 1, 0, false, 2>(
            N_U, b % 469, b / 469, AsHi, AsLo, x, nullptr, nullptr,
            wf1h, wf1l, fc1_b, nullptr, nullptr, nullptr, zHi, zLo);
    } else {
        b -= 938;
        mfma_gemm_body<128, 256, 1, 0, false, 2>(
            N_M, b % 157, b / 157, AsHi, AsLo, y, nullptr, nullptr,
            wf2h, wf2l, fc2_b, nullptr, nullptr, nullptr,
            zHi + (size_t)N_U * 256, zLo + (size_t)N_U * 256);
    }
}

// ---------------- gather aggregation + fused BN stats -------------------------------
// h pre-scaled by dinv[row]:  out[d] = bias + dinv[d]*( h'[d] + sum_{s in N(d)} h'[s] )
// Stats: per-thread register accum over its rows -> LDS reduce -> one atomic flush.
__device__ __forceinline__ void acc_bf4(float4& a, ushort4 v) {
    a.x += bf_f(v.x); a.y += bf_f(v.y); a.z += bf_f(v.z); a.w += bf_f(v.w);
}

__global__ __launch_bounds__(256) void gather256_kernel(const short* __restrict__ h,
                                                        const float* __restrict__ bias,
                                                        const float* __restrict__ dinv,
                                                        const int* __restrict__ rowptr,
                                                        const int* __restrict__ csr_src,
                                                        float* __restrict__ out,
                                                        float* __restrict__ sums,
                                                        float* __restrict__ sumsq) {
    __shared__ float shs[256], shs2[256];
    int tid = threadIdx.x;
    int wid = tid >> 6, lane = tid & 63;                   // wave per row; 4 ch/lane
    shs[tid] = 0.f; shs2[tid] = 0.f;
    __syncthreads();
    const ushort4* hp = (const ushort4*)h;                 // row stride 64 ushort4
    float4 b4 = ((const float4*)bias)[lane];
    float4 ss = {0.f, 0.f, 0.f, 0.f}, ss2 = {0.f, 0.f, 0.f, 0.f};
    for (int r = blockIdx.x * 4 + wid; r < NN; r += GBLK * 4) {
        int beg = rowptr[r], end = rowptr[r + 1];
        float dr = dinv[r];
        float4 acc = {0.f, 0.f, 0.f, 0.f};
        acc_bf4(acc, hp[(size_t)r * 64 + lane]);           // self (pre-scaled)
        int k = beg;
        for (; k + 3 < end; k += 4) {                      // 4 row loads in flight
            int s0 = csr_src[k], s1 = csr_src[k + 1], s2 = csr_src[k + 2], s3 = csr_src[k + 3];
            ushort4 v0 = hp[(size_t)s0 * 64 + lane];
            ushort4 v1 = hp[(size_t)s1 * 64 + lane];
            ushort4 v2 = hp[(size_t)s2 * 64 + lane];
            ushort4 v3 = hp[(size_t)s3 * 64 + lane];
            acc_bf4(acc, v0); acc_bf4(acc, v1); acc_bf4(acc, v2); acc_bf4(acc, v3);
        }
        for (; k < end; ++k)
            acc_bf4(acc, hp[(size_t)csr_src[k] * 64 + lane]);
        float4 o;
        o.x = b4.x + dr * acc.x; o.y = b4.y + dr * acc.y;
        o.z = b4.z + dr * acc.z; o.w = b4.w + dr * acc.w;
        ((float4*)(out + (size_t)r * 256))[lane] = o;
        ss.x += o.x; ss.y += o.y; ss.z += o.z; ss.w += o.w;
        ss2.x += o.x * o.x; ss2.y += o.y * o.y; ss2.z += o.z * o.z; ss2.w += o.w * o.w;
    }
    atomicAdd(&shs[4 * lane + 0], ss.x);  atomicAdd(&shs2[4 * lane + 0], ss2.x);
    atomicAdd(&shs[4 * lane + 1], ss.y);  atomicAdd(&shs2[4 * lane + 1], ss2.y);
    atomicAdd(&shs[4 * lane + 2], ss.z);  atomicAdd(&shs2[4 * lane + 2], ss2.z);
    atomicAdd(&shs[4 * lane + 3], ss.w);  atomicAdd(&shs2[4 * lane + 3], ss2.w);
    __syncthreads();
    atomicAdd(&sums[tid], shs[tid]);
    atomicAdd(&sumsq[tid], shs2[tid]);
}

__global__ __launch_bounds__(256) void gather128_kernel(const short* __restrict__ h,
                                                        const float* __restrict__ bias,
                                                        const float* __restrict__ dinv,
                                                        const int* __restrict__ rowptr,
                                                        const int* __restrict__ csr_src,
                                                        float* __restrict__ out) {
    int sub = threadIdx.x >> 5, lane = threadIdx.x & 31;   // half-wave per row; 4 ch/lane
    int r = blockIdx.x * 8 + sub;
    if (r >= NN) return;
    int beg = rowptr[r], end = rowptr[r + 1];
    float dr = dinv[r];
    const ushort4* hp = (const ushort4*)h;                 // row stride 32 ushort4
    float4 acc = {0.f, 0.f, 0.f, 0.f};
    acc_bf4(acc, hp[(size_t)r * 32 + lane]);
    int k = beg;
    for (; k + 3 < end; k += 4) {
        int s0 = csr_src[k], s1 = csr_src[k + 1], s2 = csr_src[k + 2], s3 = csr_src[k + 3];
        ushort4 v0 = hp[(size_t)s0 * 32 + lane];
        ushort4 v1 = hp[(size_t)s1 * 32 + lane];
        ushort4 v2 = hp[(size_t)s2 * 32 + lane];
        ushort4 v3 = hp[(size_t)s3 * 32 + lane];
        acc_bf4(acc, v0); acc_bf4(acc, v1); acc_bf4(acc, v2); acc_bf4(acc, v3);
    }
    for (; k < end; ++k)
        acc_bf4(acc, hp[(size_t)csr_src[k] * 32 + lane]);
    float4 b = ((const float4*)bias)[lane];
    float4 o;
    o.x = b.x + dr * acc.x; o.y = b.y + dr * acc.y;
    o.z = b.z + dr * acc.z; o.w = b.w + dr * acc.w;
    ((float4*)(out + (size_t)r * 128))[lane] = o;
}

// ---------------- BN finalize ----------------
__global__ void bn_final_kernel(const float* __restrict__ sums, const float* __restrict__ sumsq,
                                const float* __restrict__ gamma, const float* __restrict__ beta,
                                float* __restrict__ scale, float* __restrict__ shift) {
    int c = threadIdx.x;
    const float Nf = (float)NN;
    float mean = sums[c] / Nf;
    float var = sumsq[c] / Nf - mean * mean;
    float sc = gamma[c] * rsqrtf(var + BN_EPS);
    scale[c] = sc;
    shift[c] = beta[c] - mean * sc;
}

extern "C" void kernel_launch(void* const* d_in, const int* in_sizes, int n_in,
                              void* d_out, int out_size, void* d_ws, size_t ws_size,
                              hipStream_t stream) {
    const float* x       = (const float*)d_in[0];
    const float* y       = (const float*)d_in[1];
    const void*  ei      = d_in[2];
    const float* fc1_w   = (const float*)d_in[3];
    const float* fc1_b   = (const float*)d_in[4];
    const float* fc2_w   = (const float*)d_in[5];
    const float* fc2_b   = (const float*)d_in[6];
    const float* conv1_w = (const float*)d_in[7];
    const float* conv1_b = (const float*)d_in[8];
    const float* conv2_w = (const float*)d_in[9];
    const float* conv2_b = (const float*)d_in[10];
    const float* gamma   = (const float*)d_in[11];
    const float* beta    = (const float*)d_in[12];
    float* out = (float*)d_out;

    // Buffer ping-pong:
    //  bufB region: z0 hi/lo planes (fc out, conv1 in) -> a1 f32 (gather256 out, conv2 in)
    //  bufA region: h1' bf16 (conv1 out, gather256 in) -> h2' bf16 (conv2 out, gather128 in)
    float* ws = (float*)d_ws;
    float* bufA = ws;                       // NN*256 f32 worth
    float* bufB = ws + (size_t)NN * 256;    // NN*256 f32 worth
    float* aux  = bufB + (size_t)NN * 256;
    float* dinv  = aux;                      // NN
    float* sums  = dinv + NN;                // 256
    float* sumsq = sums + 256;               // 256
    float* scale = sumsq + 256;              // 256
    float* shift = scale + 256;              // 256
    int*   flag      = (int*)(shift + 256);  // 1
    int*   cnt       = flag + 1;             // NN
    int*   rowptr    = cnt + NN;             // NN+1
    int*   cursor    = rowptr + NN + 1;      // NN
    int*   blockSums = cursor + NN;          // NB_SCAN
    int*   csr_src   = blockSums + NB_SCAN + 3;  // EE
    // 16B-aligned fragment-ordered W buffers after csr
    short* w1th = (short*)(((uintptr_t)(csr_src + EE) + 15) & ~(uintptr_t)15);
    short* w1tl = w1th + 256 * 256;
    short* w2th = w1tl + 256 * 256;
    short* w2tl = w2th + 256 * 128;
    short* wf1h = w2tl + 256 * 128;
    short* wf1l = wf1h + 256 * 64;
    short* wf2h = wf1l + 256 * 64;
    short* wf2l = wf2h + 256 * 128;

    short* zHi = (short*)bufB;               // NN*256 bf16
    short* zLo = zHi + (size_t)NN * 256;     // NN*256 bf16 (fills rest of bufB region)
    short* hA  = (short*)bufA;               // h1'/h2' bf16 plane in bufA region
    float* a1  = bufB;                       // a1 f32 (reuses bufB after z planes die)

    // ---- CSR build + W fragment split (prep folds wsplit) ----
    prep_kernel<<<320, 256, 0, stream>>>((const int*)ei, cnt, cursor, rowptr, sums, sumsq,
                                         flag, conv1_w, conv2_w, fc1_w, fc2_w,
                                         w1th, w1tl, w2th, w2tl, wf1h, wf1l, wf2h, wf2l);
    hist_kernel<<<1024, 256, 0, stream>>>(ei, flag, cnt);
    scan1_kernel<<<NB_SCAN, 256, 0, stream>>>(cnt, rowptr, blockSums, dinv);
    scan3_kernel<<<NB_SCAN, 256, 0, stream>>>(rowptr, blockSums);
    fill_kernel<<<1024, 256, 0, stream>>>(ei, flag, rowptr, cursor, csr_src);

    // ---- input projections -> z0 hi/lo planes (one launch, ragged M guarded) ----
    fc_combined_kernel<<<1252, 256, 0, stream>>>(x, y, wf1h, wf1l, wf2h, wf2l,
                                                 fc1_b, fc2_b, zHi, zLo);

    // ---- conv1: h1' = (z0 @ W1) * dinv -> bf16 hA ----
    mfma_gemm_kernel<256, 256, 0, 1, false, 1><<<dim3(625, 2), 256, 0, stream>>>(
        NN, nullptr, zHi, zLo, w1th, w1tl, dinv, nullptr, nullptr,
        nullptr, hA, nullptr);
    // ---- gather + fused BN stats -> a1 f32, sums/sumsq ----
    gather256_kernel<<<GBLK, 256, 0, stream>>>(hA, conv1_b, dinv, rowptr, csr_src,
                                               a1, sums, sumsq);
    bn_final_kernel<<<1, 256, 0, stream>>>(sums, sumsq, gamma, beta, scale, shift);

    // ---- conv2: h2' = (relu(bn(a1)) @ W2) * dinv -> bf16 hA; gather -> out ----
    mfma_gemm_kernel<256, 128, 0, 0, true, 1><<<dim3(625, 1), 256, 0, stream>>>(
        NN, a1, nullptr, nullptr, w2th, w2tl, dinv, scale, shift,
        nullptr, hA, nullptr);
    gather128_kernel<<<NN / 8, 256, 0, stream>>>(hA, conv2_b, dinv, rowptr, csr_src, out);
}